// Round 1
// baseline (5141.048 us; speedup 1.0000x reference)
//
#include <hip/hip_runtime.h>
#include <math.h>

// TruthTransformer fwd, fp32 baseline.
// B=2 S=1024 D=1024 H=16 DK=64 L=3 FF=4096 V=32000.
// Notes:
//  - empathy bias 0.5*cos[b,h] is constant per softmax row -> softmax-invariant -> skipped.
//  - scores (B*H*S*S fp32 = 134MB) + ff (32MB) live in d_out (262MB), dead before final GEMM.
//  - d_ws usage: 5 * BS*D fp32 = 40MB (h, t0, q, k, v).

constexpr int Bc = 2, Sc = 1024, Dc = 1024, Hc = 16, Lc = 3, FFc = 4096, Vc = 32000;
constexpr int BSc = Bc * Sc;

// ---------------- embedding + noise ----------------
__global__ __launch_bounds__(256) void embed_kernel(const int* __restrict__ x,
    const float* __restrict__ noise, const float* __restrict__ emb,
    float* __restrict__ h) {
  int i = blockIdx.x * 256 + threadIdx.x;   // float4 index over BS*D/4
  int bs = i >> 8;                          // D/4 = 256 float4 per row
  int c  = i & 255;
  int tok = x[bs];
  float4 e = reinterpret_cast<const float4*>(emb)[(size_t)tok * 256 + c];
  float4 n = reinterpret_cast<const float4*>(noise)[i];
  float4 o;
  o.x = e.x + 0.05f * n.x; o.y = e.y + 0.05f * n.y;
  o.z = e.z + 0.05f * n.z; o.w = e.w + 0.05f * n.w;
  reinterpret_cast<float4*>(h)[i] = o;
}

// ---------------- SGEMM: C[M,N] = A[M,K]*W[K,N] + bias (opt ReLU) ----------------
// BM=64, BN=128, BK=16; 256 threads; 4x8 micro-tile per thread.
template<int RELU>
__device__ __forceinline__ void sgemm_body(const float* __restrict__ A,
    const float* __restrict__ W, const float* __restrict__ bias,
    float* __restrict__ C, int M, int N, int K) {
  __shared__ float As[16][68];    // [k][m], padded
  __shared__ float Bs[16][132];   // [k][n], padded
  const int t  = threadIdx.x;
  const int tx = t & 15, ty = t >> 4;
  const int bm0 = blockIdx.x * 64, bn0 = blockIdx.y * 128;

  float acc[4][8];
#pragma unroll
  for (int i = 0; i < 4; ++i)
#pragma unroll
    for (int j = 0; j < 8; ++j) acc[i][j] = 0.f;

  const int ar = t >> 2;             // A stage: row 0..63
  const int ac = (t & 3) * 4;        // k col group
  const int br = t >> 5;             // B stage: k row 0..7 (+8 for u=1)
  const int bc = (t & 31) * 4;       // n col

  for (int k0 = 0; k0 < K; k0 += 16) {
    float4 va = *reinterpret_cast<const float4*>(A + (size_t)(bm0 + ar) * K + k0 + ac);
    As[ac + 0][ar] = va.x; As[ac + 1][ar] = va.y;
    As[ac + 2][ar] = va.z; As[ac + 3][ar] = va.w;
#pragma unroll
    for (int u = 0; u < 2; ++u) {
      int rb = br + u * 8;
      *reinterpret_cast<float4*>(&Bs[rb][bc]) =
          *reinterpret_cast<const float4*>(W + (size_t)(k0 + rb) * N + bn0 + bc);
    }
    __syncthreads();
#pragma unroll
    for (int kk = 0; kk < 16; ++kk) {
      float a[4], b[8];
      *reinterpret_cast<float4*>(a)     = *reinterpret_cast<float4*>(&As[kk][ty * 4]);
      *reinterpret_cast<float4*>(b)     = *reinterpret_cast<float4*>(&Bs[kk][tx * 4]);
      *reinterpret_cast<float4*>(b + 4) = *reinterpret_cast<float4*>(&Bs[kk][64 + tx * 4]);
#pragma unroll
      for (int i = 0; i < 4; ++i)
#pragma unroll
        for (int j = 0; j < 8; ++j)
          acc[i][j] = fmaf(a[i], b[j], acc[i][j]);
    }
    __syncthreads();
  }
#pragma unroll
  for (int i = 0; i < 4; ++i) {
    int m = bm0 + ty * 4 + i;
#pragma unroll
    for (int q = 0; q < 2; ++q) {
      int n = bn0 + q * 64 + tx * 4;
      float4 o;
      o.x = acc[i][q * 4 + 0] + bias[n + 0];
      o.y = acc[i][q * 4 + 1] + bias[n + 1];
      o.z = acc[i][q * 4 + 2] + bias[n + 2];
      o.w = acc[i][q * 4 + 3] + bias[n + 3];
      if (RELU) {
        o.x = fmaxf(o.x, 0.f); o.y = fmaxf(o.y, 0.f);
        o.z = fmaxf(o.z, 0.f); o.w = fmaxf(o.w, 0.f);
      }
      *reinterpret_cast<float4*>(C + (size_t)m * N + n) = o;
    }
  }
}

template<int RELU>
__global__ __launch_bounds__(256) void sgemm_kernel(const float* __restrict__ A,
    const float* __restrict__ W, const float* __restrict__ bias,
    float* __restrict__ C, int M, int N, int K) {
  sgemm_body<RELU>(A, W, bias, C, M, N, K);
}

// fused Q/K/V projection: blockIdx.z selects the weight/out set (3x occupancy)
__global__ __launch_bounds__(256) void qkv_kernel(const float* __restrict__ h,
    const float* __restrict__ wq, const float* __restrict__ wk, const float* __restrict__ wv,
    const float* __restrict__ bq, const float* __restrict__ bk, const float* __restrict__ bv,
    float* __restrict__ q, float* __restrict__ k, float* __restrict__ v) {
  const float* W; const float* bias; float* C;
  if (blockIdx.z == 0)      { W = wq; bias = bq; C = q; }
  else if (blockIdx.z == 1) { W = wk; bias = bk; C = k; }
  else                      { W = wv; bias = bv; C = v; }
  sgemm_body<0>(h, W, bias, C, BSc, Dc, Dc);
}

// ---------------- scores[bh][s][t] = (1/8) * sum_d Q[b,s,h*64+d] * K[b,t,h*64+d] ----------------
// grid (S/64, S/64, B*H); 64x64 tile; DK=64 fully staged (transposed) in LDS.
__global__ __launch_bounds__(256) void qk_kernel(const float* __restrict__ qb,
    const float* __restrict__ kb, float* __restrict__ sc) {
  const int bh = blockIdx.z, b = bh >> 4, h = bh & 15;
  const int s0 = blockIdx.x * 64, t0 = blockIdx.y * 64;
  __shared__ float Qs[64][68];   // [d][s]
  __shared__ float Ks[64][68];   // [d][t]
  const int t  = threadIdx.x;
  const int tx = t & 15, ty = t >> 4;
#pragma unroll
  for (int u = 0; u < 4; ++u) {
    int idx = t + u * 256;
    int row = idx >> 4, cg = (idx & 15) * 4;
    float4 vq = *reinterpret_cast<const float4*>(
        qb + (size_t)(b * Sc + s0 + row) * Dc + h * 64 + cg);
    Qs[cg + 0][row] = vq.x; Qs[cg + 1][row] = vq.y;
    Qs[cg + 2][row] = vq.z; Qs[cg + 3][row] = vq.w;
    float4 vk = *reinterpret_cast<const float4*>(
        kb + (size_t)(b * Sc + t0 + row) * Dc + h * 64 + cg);
    Ks[cg + 0][row] = vk.x; Ks[cg + 1][row] = vk.y;
    Ks[cg + 2][row] = vk.z; Ks[cg + 3][row] = vk.w;
  }
  __syncthreads();
  float acc[4][4];
#pragma unroll
  for (int i = 0; i < 4; ++i)
#pragma unroll
    for (int j = 0; j < 4; ++j) acc[i][j] = 0.f;
#pragma unroll 8
  for (int d = 0; d < 64; ++d) {
    float a[4], b4[4];
    *reinterpret_cast<float4*>(a)  = *reinterpret_cast<float4*>(&Qs[d][ty * 4]);
    *reinterpret_cast<float4*>(b4) = *reinterpret_cast<float4*>(&Ks[d][tx * 4]);
#pragma unroll
    for (int i = 0; i < 4; ++i)
#pragma unroll
      for (int j = 0; j < 4; ++j)
        acc[i][j] = fmaf(a[i], b4[j], acc[i][j]);
  }
  const float scale = 0.125f;   // 1/sqrt(64)
#pragma unroll
  for (int i = 0; i < 4; ++i) {
    size_t base = ((size_t)bh * Sc + s0 + ty * 4 + i) * Sc + t0 + tx * 4;
    float4 o;
    o.x = acc[i][0] * scale; o.y = acc[i][1] * scale;
    o.z = acc[i][2] * scale; o.w = acc[i][3] * scale;
    *reinterpret_cast<float4*>(sc + base) = o;
  }
}

// ---------------- row softmax over 1024, in-place; one block per row ----------------
__global__ __launch_bounds__(256) void softmax_kernel(float* __restrict__ sc) {
  const size_t base = (size_t)blockIdx.x * Sc;
  const int t = threadIdx.x;
  float4 v = reinterpret_cast<float4*>(sc + base)[t];
  float m = fmaxf(fmaxf(v.x, v.y), fmaxf(v.z, v.w));
#pragma unroll
  for (int off = 32; off; off >>= 1) m = fmaxf(m, __shfl_xor(m, off));
  __shared__ float redm[4], reds[4];
  const int wave = t >> 6, lane = t & 63;
  if (lane == 0) redm[wave] = m;
  __syncthreads();
  m = fmaxf(fmaxf(redm[0], redm[1]), fmaxf(redm[2], redm[3]));
  float4 e;
  e.x = __expf(v.x - m); e.y = __expf(v.y - m);
  e.z = __expf(v.z - m); e.w = __expf(v.w - m);
  float s = e.x + e.y + e.z + e.w;
#pragma unroll
  for (int off = 32; off; off >>= 1) s += __shfl_xor(s, off);
  if (lane == 0) reds[wave] = s;
  __syncthreads();
  s = reds[0] + reds[1] + reds[2] + reds[3];
  float inv = 1.0f / s;
  e.x *= inv; e.y *= inv; e.z *= inv; e.w *= inv;
  reinterpret_cast<float4*>(sc + base)[t] = e;
}

// ---------------- attn[b, s, h*64+d] = sum_t P[bh][s][t] * V[b,t,h*64+d] ----------------
// grid (S/64, B*H); 64s x 64d tile; k-loop over t in chunks of 16.
__global__ __launch_bounds__(256) void pv_kernel(const float* __restrict__ sc,
    const float* __restrict__ vb, float* __restrict__ out) {
  const int bh = blockIdx.y, b = bh >> 4, h = bh & 15;
  const int s0 = blockIdx.x * 64;
  __shared__ float Ps[16][68];   // [t][s]
  __shared__ float Vs[16][64];   // [t][d]
  const int t  = threadIdx.x;
  const int tx = t & 15, ty = t >> 4;
  const int pr = t >> 2, pc = (t & 3) * 4;     // P stage: s row, t col group
  const int vr = t >> 4, vc = (t & 15) * 4;    // V stage: t row, d col
  float acc[4][4];
#pragma unroll
  for (int i = 0; i < 4; ++i)
#pragma unroll
    for (int j = 0; j < 4; ++j) acc[i][j] = 0.f;

  for (int tb = 0; tb < Sc; tb += 16) {
    float4 p4 = *reinterpret_cast<const float4*>(
        sc + ((size_t)bh * Sc + s0 + pr) * Sc + tb + pc);
    float4 v4 = *reinterpret_cast<const float4*>(
        vb + (size_t)(b * Sc + tb + vr) * Dc + h * 64 + vc);
    Ps[pc + 0][pr] = p4.x; Ps[pc + 1][pr] = p4.y;
    Ps[pc + 2][pr] = p4.z; Ps[pc + 3][pr] = p4.w;
    *reinterpret_cast<float4*>(&Vs[vr][vc]) = v4;
    __syncthreads();
#pragma unroll
    for (int kt = 0; kt < 16; ++kt) {
      float a[4], b4[4];
      *reinterpret_cast<float4*>(a)  = *reinterpret_cast<float4*>(&Ps[kt][ty * 4]);
      *reinterpret_cast<float4*>(b4) = *reinterpret_cast<float4*>(&Vs[kt][tx * 4]);
#pragma unroll
      for (int i = 0; i < 4; ++i)
#pragma unroll
        for (int j = 0; j < 4; ++j)
          acc[i][j] = fmaf(a[i], b4[j], acc[i][j]);
    }
    __syncthreads();
  }
#pragma unroll
  for (int i = 0; i < 4; ++i) {
    size_t base = (size_t)(b * Sc + s0 + ty * 4 + i) * Dc + h * 64 + tx * 4;
    float4 o; o.x = acc[i][0]; o.y = acc[i][1]; o.z = acc[i][2]; o.w = acc[i][3];
    *reinterpret_cast<float4*>(out + base) = o;
  }
}

// ---------------- out = LayerNorm(x + r) * g + be ; one block per row (in-place safe) --------
__global__ __launch_bounds__(256) void add_ln_kernel(const float* __restrict__ x,
    const float* __restrict__ r, const float* __restrict__ g,
    const float* __restrict__ be, float* __restrict__ out) {
  const size_t base = (size_t)blockIdx.x * Dc;
  const int t = threadIdx.x;
  float4 a  = reinterpret_cast<const float4*>(x + base)[t];
  float4 bb = reinterpret_cast<const float4*>(r + base)[t];
  float4 s;
  s.x = a.x + bb.x; s.y = a.y + bb.y; s.z = a.z + bb.z; s.w = a.w + bb.w;
  float sum = s.x + s.y + s.z + s.w;
  float sq  = s.x * s.x + s.y * s.y + s.z * s.z + s.w * s.w;
#pragma unroll
  for (int off = 32; off; off >>= 1) {
    sum += __shfl_xor(sum, off);
    sq  += __shfl_xor(sq, off);
  }
  __shared__ float rs[4], rq[4];
  const int wave = t >> 6, lane = t & 63;
  if (lane == 0) { rs[wave] = sum; rq[wave] = sq; }
  __syncthreads();
  sum = rs[0] + rs[1] + rs[2] + rs[3];
  sq  = rq[0] + rq[1] + rq[2] + rq[3];
  float mean = sum * (1.0f / Dc);
  float var  = sq * (1.0f / Dc) - mean * mean;
  float inv  = rsqrtf(var + 1e-5f);
  float4 gg = reinterpret_cast<const float4*>(g)[t];
  float4 bv = reinterpret_cast<const float4*>(be)[t];
  float4 o;
  o.x = (s.x - mean) * inv * gg.x + bv.x;
  o.y = (s.y - mean) * inv * gg.y + bv.y;
  o.z = (s.z - mean) * inv * gg.z + bv.z;
  o.w = (s.w - mean) * inv * gg.w + bv.w;
  reinterpret_cast<float4*>(out + base)[t] = o;
}

// ---------------- launch ----------------
extern "C" void kernel_launch(void* const* d_in, const int* in_sizes, int n_in,
                              void* d_out, int out_size, void* d_ws, size_t ws_size,
                              hipStream_t stream) {
  const int*   x     = (const int*)  d_in[0];
  const float* noise = (const float*)d_in[1];
  const float* emb   = (const float*)d_in[2];
  const float* Wq    = (const float*)d_in[3];
  const float* bq    = (const float*)d_in[4];
  const float* Wk    = (const float*)d_in[5];
  const float* bk    = (const float*)d_in[6];
  const float* Wv    = (const float*)d_in[7];
  const float* bv    = (const float*)d_in[8];
  const float* Wo    = (const float*)d_in[9];
  const float* bo    = (const float*)d_in[10];
  const float* W1f   = (const float*)d_in[11];
  const float* b1f   = (const float*)d_in[12];
  const float* W2f   = (const float*)d_in[13];
  const float* b2f   = (const float*)d_in[14];
  const float* g1    = (const float*)d_in[15];
  const float* be1   = (const float*)d_in[16];
  const float* g2    = (const float*)d_in[17];
  const float* be2   = (const float*)d_in[18];
  const float* Wout  = (const float*)d_in[19];
  const float* bout  = (const float*)d_in[20];

  const size_t HD = (size_t)BSc * Dc;            // 2M floats
  float* h  = (float*)d_ws;
  float* t0 = h  + HD;
  float* qb = t0 + HD;
  float* kb = qb + HD;
  float* vb = kb + HD;                           // total 40MB of d_ws

  float* sc = (float*)d_out;                     // 33.55M floats (scores scratch)
  float* ff = sc + (size_t)Bc * Hc * Sc * Sc;    // 8.39M floats (ffn scratch), both < out_size

  embed_kernel<<<BSc * Dc / 1024, 256, 0, stream>>>(x, noise, emb, h);

  for (int i = 0; i < Lc; ++i) {
    const float* wq = Wq + (size_t)i * Dc * Dc;
    const float* wk = Wk + (size_t)i * Dc * Dc;
    const float* wv = Wv + (size_t)i * Dc * Dc;
    const float* wo = Wo + (size_t)i * Dc * Dc;
    const float* w1 = W1f + (size_t)i * Dc * FFc;
    const float* w2 = W2f + (size_t)i * FFc * Dc;

    qkv_kernel<<<dim3(BSc / 64, Dc / 128, 3), 256, 0, stream>>>(
        h, wq, wk, wv, bq + i * Dc, bk + i * Dc, bv + i * Dc, qb, kb, vb);
    qk_kernel<<<dim3(Sc / 64, Sc / 64, Bc * Hc), 256, 0, stream>>>(qb, kb, sc);
    softmax_kernel<<<Bc * Hc * Sc, 256, 0, stream>>>(sc);
    pv_kernel<<<dim3(Sc / 64, Bc * Hc), 256, 0, stream>>>(sc, vb, qb);  // qb := attn
    sgemm_kernel<0><<<dim3(BSc / 64, Dc / 128), 256, 0, stream>>>(
        qb, wo, bo + i * Dc, t0, BSc, Dc, Dc);
    add_ln_kernel<<<BSc, 256, 0, stream>>>(h, t0, g1 + i * Dc, be1 + i * Dc, h);
    sgemm_kernel<1><<<dim3(BSc / 64, FFc / 128), 256, 0, stream>>>(
        h, w1, b1f + i * FFc, ff, BSc, FFc, Dc);
    sgemm_kernel<0><<<dim3(BSc / 64, Dc / 128), 256, 0, stream>>>(
        ff, w2, b2f + i * Dc, t0, BSc, Dc, FFc);
    add_ln_kernel<<<BSc, 256, 0, stream>>>(h, t0, g2 + i * Dc, be2 + i * Dc, h);
  }

  sgemm_kernel<0><<<dim3(BSc / 64, Vc / 128), 256, 0, stream>>>(
      h, Wout, bout, (float*)d_out, BSc, Vc, Dc);
}

// Round 3
// 2051.473 us; speedup vs baseline: 2.5060x; 2.5060x over previous
//
#include <hip/hip_runtime.h>
#include <math.h>

// TruthTransformer fwd, round 3 == round 2 resubmit (infra timeout, no signal).
// B=2 S=1024 D=1024 H=16 DK=64 L=3 FF=4096 V=32000.
//  - All matmuls via mfma_f32_16x16x32_bf16 (fp32 accum). fp32 weights are
//    converted to bf16 on the fly while staging into swizzled LDS.
//  - h (residual master), LN, softmax, residual adds stay fp32.
//  - empathy bias 0.5*cos[b,h]: constant per softmax row -> skipped.
//  - d_out scratch: scores fp32 134MB | P bf16 67MB | ff bf16 17MB (dead before final GEMM).
//  - d_ws: h 8MB | t0 8MB | hb 4MB | qb 4MB | kb 4MB | vb 4MB | attnb 4MB = 36MB.
//  - LDS tiles [row][64] bf16 (128B rows), byte ^= ((row&7)<<4) swizzle on
//    both write and read (G4 fix; conflict floor on b128 ops).

constexpr int Bc = 2, Sc = 1024, Dc = 1024, Hc = 16, Lc = 3, FFc = 4096, Vc = 32000;
constexpr int BSc = Bc * Sc;

using bf16x8 = __attribute__((ext_vector_type(8))) short;
using f32x4  = __attribute__((ext_vector_type(4))) float;

__device__ __forceinline__ unsigned short f2bf(float f) {
  unsigned u = __float_as_uint(f);
  return (unsigned short)((u + 0x7fffu + ((u >> 16) & 1u)) >> 16);
}
__device__ __forceinline__ unsigned pack2(float a, float b) {
  return (unsigned)f2bf(a) | ((unsigned)f2bf(b) << 16);
}

// ---------------- embedding + noise -> h fp32, hb bf16 ----------------
__global__ __launch_bounds__(256) void embed_kernel(const int* __restrict__ x,
    const float* __restrict__ noise, const float* __restrict__ emb,
    float* __restrict__ h, unsigned short* __restrict__ hb) {
  int i = blockIdx.x * 256 + threadIdx.x;   // float4 index over BS*D/4
  int bs = i >> 8;
  int c  = i & 255;
  int tok = x[bs];
  float4 e = reinterpret_cast<const float4*>(emb)[(size_t)tok * 256 + c];
  float4 n = reinterpret_cast<const float4*>(noise)[i];
  float4 o;
  o.x = e.x + 0.05f * n.x; o.y = e.y + 0.05f * n.y;
  o.z = e.z + 0.05f * n.z; o.w = e.w + 0.05f * n.w;
  reinterpret_cast<float4*>(h)[i] = o;
  uint2 ob; ob.x = pack2(o.x, o.y); ob.y = pack2(o.z, o.w);
  reinterpret_cast<uint2*>(hb)[i] = ob;
}

// ---------------- bf16 MFMA GEMM: C[M=2048,N] = A_bf16[M,K] * W_f32[K,N] + bias ----------------
// 128x128 tile, BK=64, 256 threads (4 waves, 2x2 of 64x64), acc 4x4 frags.
template<int N, int K, int RELU, int OBF>
__device__ __forceinline__ void gemm_body(const unsigned short* __restrict__ A,
    const float* __restrict__ W, const float* __restrict__ bias,
    void* __restrict__ Cout) {
  __shared__ unsigned short As[128 * 64];
  __shared__ unsigned short Bs[128 * 64];
  const int t    = threadIdx.x;
  const int m0   = blockIdx.x * 128, n0 = blockIdx.y * 128;
  const int wave = t >> 6, lane = t & 63;
  const int wr   = (wave >> 1) * 64, wc = (wave & 1) * 64;
  const int fr   = lane & 15, khi = lane >> 4;

  const int a_kg = (t & 7) * 8;   // k elem offset 0..56
  const int a_m  = t >> 3;        // 0..31 (+u*32)
  const int b_n  = t & 127;
  const int b_k0 = (t >> 7) * 8;  // +u*16

  f32x4 acc[4][4] = {};
  uint4 aval[4];
  float bval[32];

  auto LOADS = [&](int kt) {
#pragma unroll
    for (int u = 0; u < 4; ++u)
      aval[u] = *reinterpret_cast<const uint4*>(
          A + (size_t)(m0 + a_m + u * 32) * K + kt + a_kg);
    const float* wb = W + (size_t)kt * N + n0;
#pragma unroll
    for (int u = 0; u < 4; ++u) {
      unsigned base = (unsigned)((b_k0 + u * 16) * N) + (unsigned)b_n;
#pragma unroll
      for (int j = 0; j < 8; ++j)
        bval[u * 8 + j] = wb[base + (unsigned)(j * N)];
    }
  };

  LOADS(0);
  for (int kt = 0; kt < K; kt += 64) {
    __syncthreads();   // prev-tile LDS reads done
#pragma unroll
    for (int u = 0; u < 4; ++u) {
      int m = a_m + u * 32;
      *reinterpret_cast<uint4*>(reinterpret_cast<char*>(As) + m * 128 +
                                ((a_kg * 2) ^ ((m & 7) << 4))) = aval[u];
    }
#pragma unroll
    for (int u = 0; u < 4; ++u) {
      int k0 = b_k0 + u * 16;
      uint4 pk;
      pk.x = pack2(bval[u * 8 + 0], bval[u * 8 + 1]);
      pk.y = pack2(bval[u * 8 + 2], bval[u * 8 + 3]);
      pk.z = pack2(bval[u * 8 + 4], bval[u * 8 + 5]);
      pk.w = pack2(bval[u * 8 + 6], bval[u * 8 + 7]);
      *reinterpret_cast<uint4*>(reinterpret_cast<char*>(Bs) + b_n * 128 +
                                ((k0 * 2) ^ ((b_n & 7) << 4))) = pk;
    }
    __syncthreads();
    if (kt + 64 < K) LOADS(kt + 64);   // issue-early: next tile hides under MFMA
#pragma unroll
    for (int ks = 0; ks < 2; ++ks) {
      bf16x8 af[4], bfr[4];
#pragma unroll
      for (int i = 0; i < 4; ++i) {
        int row = wr + i * 16 + fr;
        af[i] = *reinterpret_cast<const bf16x8*>(
            reinterpret_cast<const char*>(As) + row * 128 +
            ((ks * 64 + khi * 16) ^ ((row & 7) << 4)));
        int col = wc + i * 16 + fr;
        bfr[i] = *reinterpret_cast<const bf16x8*>(
            reinterpret_cast<const char*>(Bs) + col * 128 +
            ((ks * 64 + khi * 16) ^ ((col & 7) << 4)));
      }
#pragma unroll
      for (int i = 0; i < 4; ++i)
#pragma unroll
        for (int j = 0; j < 4; ++j)
          acc[i][j] = __builtin_amdgcn_mfma_f32_16x16x32_bf16(
              af[i], bfr[j], acc[i][j], 0, 0, 0);
    }
  }
  // epilogue: C/D layout col=lane&15, row=(lane>>4)*4+reg  [m89]
#pragma unroll
  for (int j = 0; j < 4; ++j) {
    int col = n0 + wc + j * 16 + fr;
    float bv = bias[col];
#pragma unroll
    for (int i = 0; i < 4; ++i) {
      int row0 = m0 + wr + i * 16 + khi * 4;
#pragma unroll
      for (int q = 0; q < 4; ++q) {
        float o = acc[i][j][q] + bv;
        if (RELU) o = fmaxf(o, 0.f);
        if (OBF)
          ((unsigned short*)Cout)[(size_t)(row0 + q) * N + col] = f2bf(o);
        else
          ((float*)Cout)[(size_t)(row0 + q) * N + col] = o;
      }
    }
  }
}

template<int N, int K, int RELU, int OBF>
__global__ __launch_bounds__(256) void gemm_kernel(const unsigned short* __restrict__ A,
    const float* __restrict__ W, const float* __restrict__ bias, void* __restrict__ C) {
  gemm_body<N, K, RELU, OBF>(A, W, bias, C);
}

// fused QKV: blockIdx.z selects weight/bias/out
__global__ __launch_bounds__(256) void qkv_kernel(const unsigned short* __restrict__ hb,
    const float* __restrict__ wq, const float* __restrict__ wk, const float* __restrict__ wv,
    const float* __restrict__ bq, const float* __restrict__ bk, const float* __restrict__ bv,
    unsigned short* __restrict__ q, unsigned short* __restrict__ k, unsigned short* __restrict__ v) {
  const float* W; const float* bias; unsigned short* C;
  if (blockIdx.z == 0)      { W = wq; bias = bq; C = q; }
  else if (blockIdx.z == 1) { W = wk; bias = bk; C = k; }
  else                      { W = wv; bias = bv; C = v; }
  gemm_body<Dc, Dc, 0, 1>(hb, W, bias, C);
}

// ---------------- QK^T: sc[bh][s][t] = 0.125 * sum_dk Q K ; 128x128 tile, K=64 ----------------
__global__ __launch_bounds__(256) void qk_kernel(const unsigned short* __restrict__ qb,
    const unsigned short* __restrict__ kb, float* __restrict__ sc) {
  const int bh = blockIdx.z, b = bh >> 4, h = bh & 15;
  const int s0 = blockIdx.x * 128, t0 = blockIdx.y * 128;
  __shared__ unsigned short Qs[128 * 64];
  __shared__ unsigned short Ks[128 * 64];
  const int t    = threadIdx.x;
  const int wave = t >> 6, lane = t & 63;
  const int wr   = (wave >> 1) * 64, wc = (wave & 1) * 64;
  const int fr   = lane & 15, khi = lane >> 4;
  const int kg   = (t & 7) * 8, am = t >> 3;
  const size_t hbase = ((size_t)b * Sc) * Dc + (size_t)h * 64;
#pragma unroll
  for (int u = 0; u < 4; ++u) {
    int m = am + u * 32;
    uint4 qv = *reinterpret_cast<const uint4*>(qb + hbase + (size_t)(s0 + m) * Dc + kg);
    uint4 kv = *reinterpret_cast<const uint4*>(kb + hbase + (size_t)(t0 + m) * Dc + kg);
    *reinterpret_cast<uint4*>(reinterpret_cast<char*>(Qs) + m * 128 +
                              ((kg * 2) ^ ((m & 7) << 4))) = qv;
    *reinterpret_cast<uint4*>(reinterpret_cast<char*>(Ks) + m * 128 +
                              ((kg * 2) ^ ((m & 7) << 4))) = kv;
  }
  __syncthreads();
  f32x4 acc[4][4] = {};
#pragma unroll
  for (int ks = 0; ks < 2; ++ks) {
    bf16x8 af[4], bfr[4];
#pragma unroll
    for (int i = 0; i < 4; ++i) {
      int row = wr + i * 16 + fr;
      af[i] = *reinterpret_cast<const bf16x8*>(
          reinterpret_cast<const char*>(Qs) + row * 128 +
          ((ks * 64 + khi * 16) ^ ((row & 7) << 4)));
      int col = wc + i * 16 + fr;
      bfr[i] = *reinterpret_cast<const bf16x8*>(
          reinterpret_cast<const char*>(Ks) + col * 128 +
          ((ks * 64 + khi * 16) ^ ((col & 7) << 4)));
    }
#pragma unroll
    for (int i = 0; i < 4; ++i)
#pragma unroll
      for (int j = 0; j < 4; ++j)
        acc[i][j] = __builtin_amdgcn_mfma_f32_16x16x32_bf16(
            af[i], bfr[j], acc[i][j], 0, 0, 0);
  }
  float* out = sc + ((size_t)bh << 20);
#pragma unroll
  for (int j = 0; j < 4; ++j) {
    int col = t0 + wc + j * 16 + fr;
#pragma unroll
    for (int i = 0; i < 4; ++i) {
      int row0 = s0 + wr + i * 16 + khi * 4;
#pragma unroll
      for (int q = 0; q < 4; ++q)
        out[(size_t)(row0 + q) * Sc + col] = acc[i][j][q] * 0.125f;
    }
  }
}

// ---------------- row softmax fp32 -> P bf16 ----------------
__global__ __launch_bounds__(256) void softmax_kernel(const float* __restrict__ sc,
    unsigned short* __restrict__ P) {
  const size_t base = (size_t)blockIdx.x * Sc;
  const int t = threadIdx.x;
  float4 v = reinterpret_cast<const float4*>(sc + base)[t];
  float m = fmaxf(fmaxf(v.x, v.y), fmaxf(v.z, v.w));
#pragma unroll
  for (int off = 32; off; off >>= 1) m = fmaxf(m, __shfl_xor(m, off));
  __shared__ float redm[4], reds[4];
  const int wave = t >> 6, lane = t & 63;
  if (lane == 0) redm[wave] = m;
  __syncthreads();
  m = fmaxf(fmaxf(redm[0], redm[1]), fmaxf(redm[2], redm[3]));
  float4 e;
  e.x = __expf(v.x - m); e.y = __expf(v.y - m);
  e.z = __expf(v.z - m); e.w = __expf(v.w - m);
  float s = e.x + e.y + e.z + e.w;
#pragma unroll
  for (int off = 32; off; off >>= 1) s += __shfl_xor(s, off);
  if (lane == 0) reds[wave] = s;
  __syncthreads();
  s = reds[0] + reds[1] + reds[2] + reds[3];
  float inv = 1.0f / s;
  uint2 ob;
  ob.x = pack2(e.x * inv, e.y * inv);
  ob.y = pack2(e.z * inv, e.w * inv);
  reinterpret_cast<uint2*>(P + base)[t] = ob;
}

// ---------------- PV: attn[b,s,h*64+dk] = sum_t P[bh][s][t] V[b,t,h*64+dk] ----------------
// 128s x 64dk per block; 4 waves each 32x64 (2x4 frags); K-loop t in 64-chunks.
__global__ __launch_bounds__(256) void pv_kernel(const unsigned short* __restrict__ P,
    const unsigned short* __restrict__ vb, unsigned short* __restrict__ attnb) {
  const int bh = blockIdx.y, b = bh >> 4, h = bh & 15;
  const int s0 = blockIdx.x * 128;
  __shared__ unsigned short Ps[128 * 64];
  __shared__ unsigned short Vs[64 * 64];
  const int t    = threadIdx.x;
  const int wave = t >> 6, lane = t & 63;
  const int fr   = lane & 15, khi = lane >> 4;
  const int kg   = (t & 7) * 8, am = t >> 3;
  const int vn   = t & 63, vk0 = (t >> 6) * 8;   // +u*32
  f32x4 acc[2][4] = {};
  const size_t pbase = ((size_t)bh * Sc + s0) * Sc;
  const size_t vbase = ((size_t)b * Sc) * Dc + (size_t)h * 64;

  for (int kt = 0; kt < Sc; kt += 64) {
    __syncthreads();
#pragma unroll
    for (int u = 0; u < 4; ++u) {
      int m = am + u * 32;
      uint4 p4 = *reinterpret_cast<const uint4*>(P + pbase + (size_t)m * Sc + kt + kg);
      *reinterpret_cast<uint4*>(reinterpret_cast<char*>(Ps) + m * 128 +
                                ((kg * 2) ^ ((m & 7) << 4))) = p4;
    }
#pragma unroll
    for (int u = 0; u < 2; ++u) {
      int k0 = vk0 + u * 32;
      unsigned short e[8];
#pragma unroll
      for (int j = 0; j < 8; ++j)
        e[j] = vb[vbase + (size_t)(kt + k0 + j) * Dc + vn];
      uint4 w4;
      w4.x = (unsigned)e[0] | ((unsigned)e[1] << 16);
      w4.y = (unsigned)e[2] | ((unsigned)e[3] << 16);
      w4.z = (unsigned)e[4] | ((unsigned)e[5] << 16);
      w4.w = (unsigned)e[6] | ((unsigned)e[7] << 16);
      *reinterpret_cast<uint4*>(reinterpret_cast<char*>(Vs) + vn * 128 +
                                ((k0 * 2) ^ ((vn & 7) << 4))) = w4;
    }
    __syncthreads();
#pragma unroll
    for (int ks = 0; ks < 2; ++ks) {
      bf16x8 af[2], bfr[4];
#pragma unroll
      for (int i = 0; i < 2; ++i) {
        int row = wave * 32 + i * 16 + fr;
        af[i] = *reinterpret_cast<const bf16x8*>(
            reinterpret_cast<const char*>(Ps) + row * 128 +
            ((ks * 64 + khi * 16) ^ ((row & 7) << 4)));
      }
#pragma unroll
      for (int j = 0; j < 4; ++j) {
        int col = j * 16 + fr;
        bfr[j] = *reinterpret_cast<const bf16x8*>(
            reinterpret_cast<const char*>(Vs) + col * 128 +
            ((ks * 64 + khi * 16) ^ ((col & 7) << 4)));
      }
#pragma unroll
      for (int i = 0; i < 2; ++i)
#pragma unroll
        for (int j = 0; j < 4; ++j)
          acc[i][j] = __builtin_amdgcn_mfma_f32_16x16x32_bf16(
              af[i], bfr[j], acc[i][j], 0, 0, 0);
    }
  }
  unsigned short* ob = attnb + ((size_t)b * Sc + s0) * Dc + h * 64;
#pragma unroll
  for (int i = 0; i < 2; ++i) {
    int row0 = wave * 32 + i * 16 + khi * 4;
#pragma unroll
    for (int j = 0; j < 4; ++j) {
      int col = j * 16 + fr;
#pragma unroll
      for (int q = 0; q < 4; ++q)
        ob[(size_t)(row0 + q) * Dc + col] = f2bf(acc[i][j][q]);
    }
  }
}

// ---------------- out = LN(x + r)*g + be -> fp32 h and bf16 hb ----------------
__global__ __launch_bounds__(256) void add_ln_kernel(const float* __restrict__ x,
    const float* __restrict__ r, const float* __restrict__ g,
    const float* __restrict__ be, float* __restrict__ out,
    unsigned short* __restrict__ outb) {
  const size_t base = (size_t)blockIdx.x * Dc;
  const int t = threadIdx.x;
  float4 a  = reinterpret_cast<const float4*>(x + base)[t];
  float4 bb = reinterpret_cast<const float4*>(r + base)[t];
  float4 s;
  s.x = a.x + bb.x; s.y = a.y + bb.y; s.z = a.z + bb.z; s.w = a.w + bb.w;
  float sum = s.x + s.y + s.z + s.w;
  float sq  = s.x * s.x + s.y * s.y + s.z * s.z + s.w * s.w;
#pragma unroll
  for (int off = 32; off; off >>= 1) {
    sum += __shfl_xor(sum, off);
    sq  += __shfl_xor(sq, off);
  }
  __shared__ float rs[4], rq[4];
  const int wave = t >> 6, lane = t & 63;
  if (lane == 0) { rs[wave] = sum; rq[wave] = sq; }
  __syncthreads();
  sum = rs[0] + rs[1] + rs[2] + rs[3];
  sq  = rq[0] + rq[1] + rq[2] + rq[3];
  float mean = sum * (1.0f / Dc);
  float var  = sq * (1.0f / Dc) - mean * mean;
  float inv  = rsqrtf(var + 1e-5f);
  float4 gg = reinterpret_cast<const float4*>(g)[t];
  float4 bv = reinterpret_cast<const float4*>(be)[t];
  float4 o;
  o.x = (s.x - mean) * inv * gg.x + bv.x;
  o.y = (s.y - mean) * inv * gg.y + bv.y;
  o.z = (s.z - mean) * inv * gg.z + bv.z;
  o.w = (s.w - mean) * inv * gg.w + bv.w;
  reinterpret_cast<float4*>(out + base)[t] = o;
  uint2 ob2; ob2.x = pack2(o.x, o.y); ob2.y = pack2(o.z, o.w);
  reinterpret_cast<uint2*>(outb + base)[t] = ob2;
}

// ---------------- launch ----------------
extern "C" void kernel_launch(void* const* d_in, const int* in_sizes, int n_in,
                              void* d_out, int out_size, void* d_ws, size_t ws_size,
                              hipStream_t stream) {
  const int*   x     = (const int*)  d_in[0];
  const float* noise = (const float*)d_in[1];
  const float* emb   = (const float*)d_in[2];
  const float* Wq    = (const float*)d_in[3];
  const float* bq    = (const float*)d_in[4];
  const float* Wk    = (const float*)d_in[5];
  const float* bk    = (const float*)d_in[6];
  const float* Wv    = (const float*)d_in[7];
  const float* bv    = (const float*)d_in[8];
  const float* Wo    = (const float*)d_in[9];
  const float* bo    = (const float*)d_in[10];
  const float* W1f   = (const float*)d_in[11];
  const float* b1f   = (const float*)d_in[12];
  const float* W2f   = (const float*)d_in[13];
  const float* b2f   = (const float*)d_in[14];
  const float* g1    = (const float*)d_in[15];
  const float* be1   = (const float*)d_in[16];
  const float* g2    = (const float*)d_in[17];
  const float* be2   = (const float*)d_in[18];
  const float* Wout  = (const float*)d_in[19];
  const float* bout  = (const float*)d_in[20];

  const size_t HD = (size_t)BSc * Dc;                  // 2M elems
  float* h  = (float*)d_ws;
  float* t0 = h + HD;
  unsigned short* hb    = (unsigned short*)(t0 + HD);
  unsigned short* qb2   = hb + HD;
  unsigned short* kb2   = qb2 + HD;
  unsigned short* vb2   = kb2 + HD;
  unsigned short* attnb = vb2 + HD;                    // 36 MB total

  float* sc = (float*)d_out;                           // 32M floats
  unsigned short* P   = (unsigned short*)(sc + (size_t)Bc * Hc * Sc * Sc);
  unsigned short* ffb = P + (size_t)Bc * Hc * Sc * Sc; // 2048x4096 bf16

  embed_kernel<<<BSc * Dc / 1024, 256, 0, stream>>>(x, noise, emb, h, hb);

  for (int i = 0; i < Lc; ++i) {
    const float* wq = Wq + (size_t)i * Dc * Dc;
    const float* wk = Wk + (size_t)i * Dc * Dc;
    const float* wv = Wv + (size_t)i * Dc * Dc;
    const float* wo = Wo + (size_t)i * Dc * Dc;
    const float* w1 = W1f + (size_t)i * Dc * FFc;
    const float* w2 = W2f + (size_t)i * FFc * Dc;

    qkv_kernel<<<dim3(BSc / 128, Dc / 128, 3), 256, 0, stream>>>(
        hb, wq, wk, wv, bq + i * Dc, bk + i * Dc, bv + i * Dc, qb2, kb2, vb2);
    qk_kernel<<<dim3(Sc / 128, Sc / 128, Bc * Hc), 256, 0, stream>>>(qb2, kb2, sc);
    softmax_kernel<<<Bc * Hc * Sc, 256, 0, stream>>>(sc, P);
    pv_kernel<<<dim3(Sc / 128, Bc * Hc), 256, 0, stream>>>(P, vb2, attnb);
    gemm_kernel<Dc, Dc, 0, 0><<<dim3(BSc / 128, Dc / 128), 256, 0, stream>>>(
        attnb, wo, bo + i * Dc, t0);
    add_ln_kernel<<<BSc, 256, 0, stream>>>(h, t0, g1 + i * Dc, be1 + i * Dc, h, hb);
    gemm_kernel<FFc, Dc, 1, 1><<<dim3(BSc / 128, FFc / 128), 256, 0, stream>>>(
        hb, w1, b1f + i * FFc, ffb);
    gemm_kernel<Dc, FFc, 0, 0><<<dim3(BSc / 128, Dc / 128), 256, 0, stream>>>(
        ffb, w2, b2f + i * Dc, t0);
    add_ln_kernel<<<BSc, 256, 0, stream>>>(h, t0, g2 + i * Dc, be2 + i * Dc, h, hb);
  }

  gemm_kernel<Vc, Dc, 0, 0><<<dim3(BSc / 128, Vc / 128), 256, 0, stream>>>(
      hb, Wout, bout, (float*)d_out);
}